// Round 19
// baseline (121.119 us; speedup 1.0000x reference)
//
#include <hip/hip_runtime.h>

typedef __bf16 bf16;
typedef __attribute__((ext_vector_type(4))) __bf16 bf16x4;
typedef __attribute__((ext_vector_type(8))) __bf16 bf16x8;
typedef __attribute__((ext_vector_type(4))) float f32x4;
typedef unsigned int u32;

#define MFMA16(a, b, c) __builtin_amdgcn_mfma_f32_16x16x32_bf16((a), (b), (c), 0, 0, 0)
#define LOG2E 1.4426950408889634f

// KV chunk, per (b, kt=0..7): 81920 bytes =
//  [0,16384): K packed in FRAGMENT order: byte qt<<11 | h<<10 | L<<4 | j<<1
//     (L = lane) holds K[row R(qt,l16)][o=32h+8u+j] — lane L loading
//     qt<<11 (+1024) + L<<4 gets its S A-frag directly (L1-shared).
//  [16384,81920): V packed for direct wave-frag loads: octet (c, mm) at
//     16384 + (c>>6)<<14 + (mm>>2)<<12 + ((c>>4)&3)<<10 + (mm&3)<<8 +
//     (c&15)<<4. Loading (cg<<14)+(k<<10)+(lane<<4), k=4kb+ct yields A-frag
//     (c = 64*cg + 16*ct + l16, octet mm = 4kb+u).

// ---------------------------------------------------------------------------
// Kernel 1: fused V-pack + W prep (R12 verbatim).
// ---------------------------------------------------------------------------
__global__ __launch_bounds__(256) void vprep_kernel(const float* __restrict__ kf,
                                                    const float* __restrict__ Wq,
                                                    const float* __restrict__ Wk,
                                                    const int* __restrict__ flag,
                                                    bf16* __restrict__ KV,
                                                    bf16* __restrict__ Wbh,
                                                    bf16* __restrict__ Wbl) {
  const int bid = blockIdx.x, t = threadIdx.x;
  if (bid < 4096) {
    int i = (bid << 8) + t;  // (b, c, q8)
    int q8 = i & 127, c = (i >> 7) & 255, b = i >> 15;
    const float* src = kf + ((size_t)(((b << 8) + c)) << 10) + (q8 << 3);
    float4 f0 = *(const float4*)src;
    float4 f1 = *(const float4*)(src + 4);
    bf16x8 v;
    v[0] = (bf16)f0.x; v[1] = (bf16)f0.y; v[2] = (bf16)f0.z; v[3] = (bf16)f0.w;
    v[4] = (bf16)f1.x; v[5] = (bf16)f1.y; v[6] = (bf16)f1.z; v[7] = (bf16)f1.w;
    int kt = q8 >> 4, mm = q8 & 15;
    char* dst = (char*)KV + (size_t)((b << 3) + kt) * 81920 + 16384 +
                ((c >> 6) << 14) + ((mm >> 2) << 12) + (((c >> 4) & 3) << 10) +
                ((mm & 3) << 8) + ((c & 15) << 4);
    *(bf16x8*)dst = v;
  } else {
    int bx = bid - 4096;  // 0..31
    int z = bx >> 4;
    const float* src = (z == 0) ? Wq : ((flag[0] != 0) ? Wq : Wk);
    const float sc = (z == 0) ? LOG2E : 1.0f;  // exp2-domain softmax
    int i = ((((bx & 15) << 8) + t) << 2);
    float4 vv = *(const float4*)(src + i);
    vv.x *= sc; vv.y *= sc; vv.z *= sc; vv.w *= sc;
    bf16x4 hi, lo;
    hi[0] = (bf16)vv.x; lo[0] = (bf16)(vv.x - (float)hi[0]);
    hi[1] = (bf16)vv.y; lo[1] = (bf16)(vv.y - (float)hi[1]);
    hi[2] = (bf16)vv.z; lo[2] = (bf16)(vv.z - (float)hi[2]);
    hi[3] = (bf16)vv.w; lo[3] = (bf16)(vv.w - (float)hi[3]);
    *(bf16x4*)(Wbh + (z << 14) + i) = hi;
    *(bf16x4*)(Wbl + (z << 14) + i) = lo;
  }
}

// ---------------------------------------------------------------------------
// Kernel 2: MFMA projection (R16 verbatim). z=0 -> Qp (log2e-scaled);
// z=1 -> KV K-part in FRAGMENT-packed order; B-frags from packed KV V-region.
// ---------------------------------------------------------------------------
__global__ __launch_bounds__(256) void proj_kernel(const float* __restrict__ qf,
                                                   const bf16* __restrict__ Wbh,
                                                   const bf16* __restrict__ Wbl,
                                                   const float* __restrict__ bq,
                                                   const float* __restrict__ bk,
                                                   const int* __restrict__ flag,
                                                   bf16* __restrict__ Qp,
                                                   bf16* __restrict__ KV) {
  const int b = blockIdx.y, z = blockIdx.z;
  const bf16* Wh = Wbh + z * 16384;
  const bf16* Wl = Wbl + z * 16384;
  const float* bias = z ? (flag[0] ? bq : bk) : bq;

  const int t = threadIdx.x;
  const int w = t >> 6, lane = t & 63;
  const int g = lane >> 4, l16 = lane & 15;
  const int wo = w >> 1, wp = w & 1;
  const int o0 = wo << 5;
  const int pbase = (blockIdx.x << 7) + (wp << 6);

  f32x4 acc[2][4];
#pragma unroll
  for (int ot = 0; ot < 2; ++ot) {
    float4 bv = *(const float4*)(bias + o0 + (ot << 4) + (g << 2));
    if (z == 0) { bv.x *= LOG2E; bv.y *= LOG2E; bv.z *= LOG2E; bv.w *= LOG2E; }
#pragma unroll
    for (int pt = 0; pt < 4; ++pt) acc[ot][pt] = (f32x4){bv.x, bv.y, bv.z, bv.w};
  }

  const float* xb = qf + ((((b << 8) + (g << 3)) << 10) + pbase + l16);
  const bf16* whb = Wh + ((o0 + l16) << 8) + (g << 3);
  const bf16* wlb = Wl + ((o0 + l16) << 8) + (g << 3);

  for (int kk = 0; kk < 8; ++kk) {
    bf16x8 ah[2], al[2];
#pragma unroll
    for (int ot = 0; ot < 2; ++ot) {
      ah[ot] = *(const bf16x8*)(whb + (ot << 12) + (kk << 5));
      al[ot] = *(const bf16x8*)(wlb + (ot << 12) + (kk << 5));
    }
#pragma unroll
    for (int pt = 0; pt < 4; ++pt) {
      bf16x8 xf;
      if (z == 0) {
        const float* xk = xb + (kk << 15);
        float xv[8];
#pragma unroll
        for (int j = 0; j < 8; ++j) xv[j] = xk[(j << 10) + (pt << 4)];
#pragma unroll
        for (int j = 0; j < 8; ++j) xf[j] = (bf16)xv[j];
      } else {
        // c = kk*32+8g+j ; p = pbase+16pt+l16 ; kt = p>>7, q'=p&127
        const int p = pbase + (pt << 4) + l16;
        const int mm = (p & 127) >> 3, e = p & 7;
        const char* vp = (const char*)KV + (size_t)((b << 3) + (p >> 7)) * 81920 +
                         16384 + ((kk >> 1) << 14) + ((mm >> 2) << 12) +
                         ((((kk & 1) << 1) + (g >> 1)) << 10) + ((mm & 3) << 8) +
                         (((g & 1) << 3) << 4) + (e << 1);
#pragma unroll
        for (int j = 0; j < 8; ++j)
          xf[j] = *(const bf16*)(vp + (j << 4));
      }
#pragma unroll
      for (int ot = 0; ot < 2; ++ot) {
        acc[ot][pt] = MFMA16(ah[ot], xf, acc[ot][pt]);
        acc[ot][pt] = MFMA16(al[ot], xf, acc[ot][pt]);
      }
    }
  }

#pragma unroll
  for (int ot = 0; ot < 2; ++ot)
#pragma unroll
    for (int pt = 0; pt < 4; ++pt) {
      bf16x4 q4;
#pragma unroll
      for (int r = 0; r < 4; ++r) q4[r] = (bf16)acc[ot][pt][r];
      int p = pbase + (pt << 4) + l16;
      if (z == 0) {
        *(bf16x4*)(Qp + ((((b << 10) + p)) << 6) + o0 + (ot << 4) + (g << 2)) = q4;
      } else {
        // K fragment-pack: q -> (qt, kl16); o = 32wo+16ot+4g+r
        int kt = p >> 7, q = p & 127;
        int qt = (q & 1) | ((q >> 5) << 1);
        int kl16 = (((q >> 3) & 3) << 2) | ((q >> 1) & 3);
        char* dst = (char*)KV + (size_t)((b << 3) + kt) * 81920 + (qt << 11) +
                    (wo << 10) + (((ot << 1) + (g >> 1)) << 8) + (kl16 << 4) +
                    ((g & 1) << 3);
        *(bf16x4*)dst = q4;
      }
    }
}

// ---------------------------------------------------------------------------
// Kernel 3: fused flash attention — ZERO LDS, ZERO barriers, P in-register.
// grid 1024 (XCD-swz) x 256 thr: (b, ptile, ch-half). Wave w owns px-group
// [64*ptile + 16w, +16) end-to-end: S (dup across ch-halves; MFMA pipe idle)
// + no-max exp2 softmax (per-lane l_) + PV for 128 ch. Lane (u,l16) holds
// kv-octets {u,4+u,8+u,12+u} after S == exactly its PV B-frag octets, so P
// packs in-lane. K/V stream as fragment-packed coalesced 1KB wave-reads
// (L1-shared within block). ~12 waves/CU of pure TLP.
// ---------------------------------------------------------------------------
__global__ __launch_bounds__(256, 2) void attn_kernel(const bf16* __restrict__ KV,
                                                      const bf16* __restrict__ Qp,
                                                      float* __restrict__ out) {
  const int bid = blockIdx.x;
  const int wkid = ((bid & 7) << 7) + (bid >> 3);  // bijective: 1024 % 8 == 0
  const int b = wkid >> 5, sub = wkid & 31;
  const int ptile = sub >> 1, ch = sub & 1;
  const int p0 = ptile << 6;
  const int t = threadIdx.x;
  const int w = t >> 6, lane = t & 63;
  const int u = lane >> 4, l16 = lane & 15;
  const int px = p0 + (w << 4) + l16;

  // Q B-fragments for this wave's 16 px (col=px, k=o)
  const bf16* qb = Qp + (((size_t)((b << 10) + px)) << 6) + (u << 3);
  const bf16x8 qa0 = *(const bf16x8*)qb;
  const bf16x8 qa1 = *(const bf16x8*)(qb + 32);

  const char* chunk0 = (const char*)KV + (size_t)b * (8 * 81920);

  f32x4 acc[8];  // [(cgi<<2)+ct]: c = 128ch + 64cgi + 16ct + 4u + r
#pragma unroll
  for (int i = 0; i < 8; ++i) acc[i] = (f32x4){0.f, 0.f, 0.f, 0.f};
  float l_ = 0.f;

  for (int kt = 0; kt < 8; ++kt) {
    const char* kbase = chunk0 + kt * 81920 + (lane << 4);

    // ---- S^T = K·Q^T: K A-frags direct from fragment-packed global ----
    f32x4 s[8];
#pragma unroll
    for (int h = 0; h < 2; ++h) {
      bf16x8 kr0[4], kr1[4];
#pragma unroll
      for (int q4i = 0; q4i < 4; ++q4i) {
        const char* kq = kbase + (((h << 2) + q4i) << 11);
        kr0[q4i] = *(const bf16x8*)kq;
        kr1[q4i] = *(const bf16x8*)(kq + 1024);
      }
#pragma unroll
      for (int q4i = 0; q4i < 4; ++q4i) {
        f32x4 z = (f32x4){0.f, 0.f, 0.f, 0.f};
        z = MFMA16(kr0[q4i], qa0, z);
        s[(h << 2) + q4i] = MFMA16(kr1[q4i], qa1, z);
      }
    }
    // ---- NO-MAX softmax: P = exp2(S); l += sum (4-lane row reduce) ----
#pragma unroll
    for (int qt = 0; qt < 8; ++qt)
#pragma unroll
      for (int r = 0; r < 4; ++r) s[qt][r] = exp2f(s[qt][r]);
    float rs = 0.f;
#pragma unroll
    for (int qt = 0; qt < 8; ++qt)
      rs += (s[qt][0] + s[qt][1]) + (s[qt][2] + s[qt][3]);
    rs += __shfl_xor(rs, 16);
    rs += __shfl_xor(rs, 32);
    l_ += rs;
    // ---- P -> bf16 B-frags fully IN-LANE: pb[kb] covers kv-octet 4kb+u ----
    bf16x8 pb[4];
#pragma unroll
    for (int kb = 0; kb < 4; ++kb)
#pragma unroll
      for (int r = 0; r < 4; ++r) {
        pb[kb][2 * r] = (bf16)s[2 * kb][r];
        pb[kb][2 * r + 1] = (bf16)s[2 * kb + 1][r];
      }
    // ---- PV: V A-frags direct from packed global; 32 mfma ----
    const char* vs0 = chunk0 + kt * 81920 + 16384 + (((ch << 1)) << 14) + (lane << 4);
#pragma unroll
    for (int cgi = 0; cgi < 2; ++cgi) {
      const char* vsrc = vs0 + (cgi << 14);
#pragma unroll
      for (int kb = 0; kb < 4; ++kb) {
#pragma unroll
        for (int ct = 0; ct < 4; ++ct) {
          bf16x8 va = *(const bf16x8*)(vsrc + (((kb << 2) + ct) << 10));
          acc[(cgi << 2) + ct] = MFMA16(va, pb[kb], acc[(cgi << 2) + ct]);
        }
      }
    }
  }

  // ---- epilogue: per-lane normalize (l_ is this px's own sum), store ----
  const float inv = 1.f / l_;
  float* ob = out + ((size_t)b << 18) + px;
#pragma unroll
  for (int cgi = 0; cgi < 2; ++cgi)
#pragma unroll
    for (int ct = 0; ct < 4; ++ct)
#pragma unroll
      for (int r = 0; r < 4; ++r) {
        int c = (ch << 7) + (cgi << 6) + (ct << 4) + (u << 2) + r;
        ob[(size_t)c << 10] = acc[(cgi << 2) + ct][r] * inv;
      }
}

// ---------------------------------------------------------------------------
extern "C" void kernel_launch(void* const* d_in, const int* in_sizes, int n_in,
                              void* d_out, int out_size, void* d_ws, size_t ws_size,
                              hipStream_t stream) {
  const float* qf = (const float*)d_in[0];
  const float* kf = (const float*)d_in[1];
  const float* Wq = (const float*)d_in[2];
  const float* bq = (const float*)d_in[3];
  const float* Wk = (const float*)d_in[4];
  const float* bk = (const float*)d_in[5];
  // d_in[6] = vis_CA (unused)
  const int* flag = (const int*)d_in[7];  // same_WqWk
  float* out = (float*)d_out;

  char* ws = (char*)d_ws;
  bf16* Qp = (bf16*)ws;                          // 4 MiB: [32][1024][64] bf16
  bf16* Wbh = (bf16*)(ws + (4u << 20));          // 64 KiB
  bf16* Wbl = (bf16*)(ws + (4u << 20) + 65536);  // 64 KiB
  bf16* KV = (bf16*)(ws + (5u << 20));           // 20 MiB: [32][8] x 81920B chunks

  vprep_kernel<<<4128, 256, 0, stream>>>(kf, Wq, Wk, flag, KV, Wbh, Wbl);
  proj_kernel<<<dim3(8, 32, 2), 256, 0, stream>>>(qf, Wbh, Wbl, bq, bk, flag, Qp, KV);
  attn_kernel<<<1024, 256, 0, stream>>>(KV, Qp, out);
}

// Round 20
// 71.471 us; speedup vs baseline: 1.6947x; 1.6947x over previous
//
#include <hip/hip_runtime.h>

typedef __bf16 bf16;
typedef __attribute__((ext_vector_type(4))) __bf16 bf16x4;
typedef __attribute__((ext_vector_type(8))) __bf16 bf16x8;
typedef __attribute__((ext_vector_type(4))) float f32x4;
typedef unsigned int u32;

#define MFMA16(a, b, c) __builtin_amdgcn_mfma_f32_16x16x32_bf16((a), (b), (c), 0, 0, 0)
#define LOG2E 1.4426950408889634f
#define AS1 __attribute__((address_space(1)))
#define AS3 __attribute__((address_space(3)))
#define GLL16(g, l) __builtin_amdgcn_global_load_lds((const AS1 u32*)(g), (AS3 u32*)(l), 16, 0, 0)

// KV chunk, per (b, kt=0..7): 81920 bytes =
//  [0,16384):     K tile [128 q][64 o] bf16, identity rows, 16B-blk swz ^(q&7)
//  [16384,81920): V packed for DIRECT wave-fragment loads: octet (c, mm)
//     (mm = kv>>3 within chunk) at byte 16384 + (c>>6)<<14 + (mm>>2)<<12 +
//     ((c>>4)&3)<<10 + (mm&3)<<8 + (c&15)<<4.  attn wave w: load k=4kb+ct at
//     (w<<14)+(k<<10)+(lane<<4) == A-frag (c=64w+16ct+l16, octet mm=4kb+u).

// ---------------------------------------------------------------------------
// Kernel 1: fused V-pack + W prep (R12 verbatim).
// ---------------------------------------------------------------------------
__global__ __launch_bounds__(256) void vprep_kernel(const float* __restrict__ kf,
                                                    const float* __restrict__ Wq,
                                                    const float* __restrict__ Wk,
                                                    const int* __restrict__ flag,
                                                    bf16* __restrict__ KV,
                                                    bf16* __restrict__ Wbh,
                                                    bf16* __restrict__ Wbl) {
  const int bid = blockIdx.x, t = threadIdx.x;
  if (bid < 4096) {
    int i = (bid << 8) + t;  // (b, c, q8)
    int q8 = i & 127, c = (i >> 7) & 255, b = i >> 15;
    const float* src = kf + ((size_t)(((b << 8) + c)) << 10) + (q8 << 3);
    float4 f0 = *(const float4*)src;
    float4 f1 = *(const float4*)(src + 4);
    bf16x8 v;
    v[0] = (bf16)f0.x; v[1] = (bf16)f0.y; v[2] = (bf16)f0.z; v[3] = (bf16)f0.w;
    v[4] = (bf16)f1.x; v[5] = (bf16)f1.y; v[6] = (bf16)f1.z; v[7] = (bf16)f1.w;
    int kt = q8 >> 4, mm = q8 & 15;
    char* dst = (char*)KV + (size_t)((b << 3) + kt) * 81920 + 16384 +
                ((c >> 6) << 14) + ((mm >> 2) << 12) + (((c >> 4) & 3) << 10) +
                ((mm & 3) << 8) + ((c & 15) << 4);
    *(bf16x8*)dst = v;
  } else {
    int bx = bid - 4096;  // 0..31
    int z = bx >> 4;
    const float* src = (z == 0) ? Wq : ((flag[0] != 0) ? Wq : Wk);
    const float sc = (z == 0) ? LOG2E : 1.0f;  // exp2-domain softmax
    int i = ((((bx & 15) << 8) + t) << 2);
    float4 vv = *(const float4*)(src + i);
    vv.x *= sc; vv.y *= sc; vv.z *= sc; vv.w *= sc;
    bf16x4 hi, lo;
    hi[0] = (bf16)vv.x; lo[0] = (bf16)(vv.x - (float)hi[0]);
    hi[1] = (bf16)vv.y; lo[1] = (bf16)(vv.y - (float)hi[1]);
    hi[2] = (bf16)vv.z; lo[2] = (bf16)(vv.z - (float)hi[2]);
    hi[3] = (bf16)vv.w; lo[3] = (bf16)(vv.w - (float)hi[3]);
    *(bf16x4*)(Wbh + (z << 14) + i) = hi;
    *(bf16x4*)(Wbl + (z << 14) + i) = lo;
  }
}

// ---------------------------------------------------------------------------
// Kernel 2: MFMA projection (R12 verbatim). z=0 -> Qp (log2e-scaled, reads qf
// fp32); z=1 -> KV K-part. z=1 B-frags read bf16 from packed KV V-region.
// ---------------------------------------------------------------------------
__global__ __launch_bounds__(256) void proj_kernel(const float* __restrict__ qf,
                                                   const bf16* __restrict__ Wbh,
                                                   const bf16* __restrict__ Wbl,
                                                   const float* __restrict__ bq,
                                                   const float* __restrict__ bk,
                                                   const int* __restrict__ flag,
                                                   bf16* __restrict__ Qp,
                                                   bf16* __restrict__ KV) {
  const int b = blockIdx.y, z = blockIdx.z;
  const bf16* Wh = Wbh + z * 16384;
  const bf16* Wl = Wbl + z * 16384;
  const float* bias = z ? (flag[0] ? bq : bk) : bq;

  const int t = threadIdx.x;
  const int w = t >> 6, lane = t & 63;
  const int g = lane >> 4, l16 = lane & 15;
  const int wo = w >> 1, wp = w & 1;
  const int o0 = wo << 5;
  const int pbase = (blockIdx.x << 7) + (wp << 6);

  f32x4 acc[2][4];
#pragma unroll
  for (int ot = 0; ot < 2; ++ot) {
    float4 bv = *(const float4*)(bias + o0 + (ot << 4) + (g << 2));
    if (z == 0) { bv.x *= LOG2E; bv.y *= LOG2E; bv.z *= LOG2E; bv.w *= LOG2E; }
#pragma unroll
    for (int pt = 0; pt < 4; ++pt) acc[ot][pt] = (f32x4){bv.x, bv.y, bv.z, bv.w};
  }

  const float* xb = qf + ((((b << 8) + (g << 3)) << 10) + pbase + l16);
  const bf16* whb = Wh + ((o0 + l16) << 8) + (g << 3);
  const bf16* wlb = Wl + ((o0 + l16) << 8) + (g << 3);

  for (int kk = 0; kk < 8; ++kk) {
    bf16x8 ah[2], al[2];
#pragma unroll
    for (int ot = 0; ot < 2; ++ot) {
      ah[ot] = *(const bf16x8*)(whb + (ot << 12) + (kk << 5));
      al[ot] = *(const bf16x8*)(wlb + (ot << 12) + (kk << 5));
    }
#pragma unroll
    for (int pt = 0; pt < 4; ++pt) {
      bf16x8 xf;
      if (z == 0) {
        const float* xk = xb + (kk << 15);
        float xv[8];
#pragma unroll
        for (int j = 0; j < 8; ++j) xv[j] = xk[(j << 10) + (pt << 4)];
#pragma unroll
        for (int j = 0; j < 8; ++j) xf[j] = (bf16)xv[j];
      } else {
        // c = kk*32+8g+j ; p = pbase+16pt+l16 ; kt = p>>7, q'=p&127
        const int p = pbase + (pt << 4) + l16;
        const int mm = (p & 127) >> 3, e = p & 7;
        const char* vp = (const char*)KV + (size_t)((b << 3) + (p >> 7)) * 81920 +
                         16384 + ((kk >> 1) << 14) + ((mm >> 2) << 12) +
                         ((((kk & 1) << 1) + (g >> 1)) << 10) + ((mm & 3) << 8) +
                         (((g & 1) << 3) << 4) + (e << 1);
#pragma unroll
        for (int j = 0; j < 8; ++j)
          xf[j] = *(const bf16*)(vp + (j << 4));
      }
#pragma unroll
      for (int ot = 0; ot < 2; ++ot) {
        acc[ot][pt] = MFMA16(ah[ot], xf, acc[ot][pt]);
        acc[ot][pt] = MFMA16(al[ot], xf, acc[ot][pt]);
      }
    }
  }

#pragma unroll
  for (int ot = 0; ot < 2; ++ot)
#pragma unroll
    for (int pt = 0; pt < 4; ++pt) {
      bf16x4 q4;
#pragma unroll
      for (int r = 0; r < 4; ++r) q4[r] = (bf16)acc[ot][pt][r];
      int p = pbase + (pt << 4) + l16;
      if (z == 0) {
        *(bf16x4*)(Qp + ((((b << 10) + p)) << 6) + o0 + (ot << 4) + (g << 2)) = q4;
      } else {
        int kt = p >> 7, q = p & 127;
        int blk = (o0 >> 3) + (ot << 1) + (g >> 1);
        char* dst = (char*)KV + (size_t)((b << 3) + kt) * 81920 + q * 128 +
                    16 * (blk ^ (q & 7)) + ((g & 1) << 3);
        *(bf16x4*)dst = q4;
      }
    }
}

// ---------------------------------------------------------------------------
// Kernel 3: fused flash attention (R12 verbatim + T5 setprio around MFMA
// clusters). grid 512 (XCD-swz) x 256 thr. KVBLK=128, 8 iters, no-max exp2
// softmax, V global->VGPR packed frags, P via sP, K gll dbuf, 2 barriers/it.
// ---------------------------------------------------------------------------
__global__ __launch_bounds__(256, 2) void attn_kernel(const bf16* __restrict__ KV,
                                                      const bf16* __restrict__ Qp,
                                                      float* __restrict__ out) {
  const int bid = blockIdx.x;
  const int wkid = ((bid & 7) << 6) + (bid >> 3);  // bijective: 512 % 8 == 0
  const int b = wkid >> 4, ptile = wkid & 15;
  const int p0 = ptile << 6;
  const int t = threadIdx.x;
  const int w = t >> 6, lane = t & 63;
  const int u = lane >> 4, l16 = lane & 15;

  __shared__ __align__(16) unsigned char sK[2][16384];  // K dbuf (gll target)
  __shared__ __align__(16) unsigned char sP[16384];     // [64 px][128 kv], swz
  __shared__ float sL[64];

  // Q B-fragments for this wave's 16 px (col=px, k=o)
  const bf16* qb = Qp + (((size_t)((b << 10) + p0 + (w << 4) + l16)) << 6) + (u << 3);
  const bf16x8 qa0 = *(const bf16x8*)qb;
  const bf16x8 qa1 = *(const bf16x8*)(qb + 32);

  const char* chunk0 = (const char*)KV + (size_t)b * (8 * 81920);
  const int Rb = ((l16 >> 2) << 3) + ((l16 & 3) << 1);  // K row perm base

  f32x4 acc[4][4];  // [pg][ct]: c = 64w + 16ct + 4u + r ; px = 16pg + l16
#pragma unroll
  for (int i = 0; i < 4; ++i)
#pragma unroll
    for (int j = 0; j < 4; ++j) acc[i][j] = (f32x4){0.f, 0.f, 0.f, 0.f};
  float l_ = 0.f;

  const int prow = (w << 4) + l16, pswz = prow & 7;

  // ---- prologue: stage K_0 (4 gll/wave) ----
  {
    const char* g = chunk0 + (w << 12) + (lane << 4);
    unsigned char* l = sK[0] + (w << 12);
#pragma unroll
    for (int op = 0; op < 4; ++op) GLL16(g + op * 1024, l + op * 1024);
  }
  asm volatile("s_waitcnt vmcnt(0)" ::: "memory");
  __syncthreads();

  int cur = 0;
  for (int kt = 0; kt < 8; ++kt) {
    // ---- V_t -> regs: 16 coalesced 1KB loads (packed A-fragments) ----
    bf16x8 vr[16];  // vr[4kb+ct] = V A-frag (c=64w+16ct+l16, octet 4kb+u)
    const char* vsrc = chunk0 + kt * 81920 + 16384 + (w << 14) + (lane << 4);
#pragma unroll
    for (int k = 0; k < 16; ++k) vr[k] = *(const bf16x8*)(vsrc + (k << 10));
    // ---- K_{t+1} gll into other buffer ----
    if (kt < 7) {
      const char* g = chunk0 + (kt + 1) * 81920 + (w << 12) + (lane << 4);
      unsigned char* l = sK[cur ^ 1] + (w << 12);
#pragma unroll
      for (int op = 0; op < 4; ++op) GLL16(g + op * 1024, l + op * 1024);
    }
    const unsigned char* sKc = sK[cur];

    // ---- S^T = K·Q^T (16 mfma, permuted K rows from swizzled LDS) ----
    __builtin_amdgcn_s_setprio(1);
    f32x4 s[8];
#pragma unroll
    for (int qt = 0; qt < 8; ++qt) {
      const int R = Rb + (qt & 1) + ((qt >> 1) << 5);
      const int rb = R * 128;
      bf16x8 k0 = *(const bf16x8*)(sKc + rb + 16 * (u ^ (R & 7)));
      bf16x8 k1 = *(const bf16x8*)(sKc + rb + 16 * ((u + 4) ^ (R & 7)));
      f32x4 z = (f32x4){0.f, 0.f, 0.f, 0.f};
      z = MFMA16(k0, qa0, z);
      s[qt] = MFMA16(k1, qa1, z);
    }
    __builtin_amdgcn_s_setprio(0);
    // ---- NO-MAX softmax: P = exp2(S); l += sum ----
#pragma unroll
    for (int qt = 0; qt < 8; ++qt)
#pragma unroll
      for (int r = 0; r < 4; ++r) s[qt][r] = exp2f(s[qt][r]);
    float rs = 0.f;
#pragma unroll
    for (int qt = 0; qt < 8; ++qt)
      rs += (s[qt][0] + s[qt][1]) + (s[qt][2] + s[qt][3]);
    rs += __shfl_xor(rs, 16);
    rs += __shfl_xor(rs, 32);
    l_ += rs;
    // ---- P -> bf16 octets (in-lane), publish 4 b128 ----
#pragma unroll
    for (int a = 0; a < 4; ++a) {
      bf16x8 pb;
#pragma unroll
      for (int r = 0; r < 4; ++r) {
        pb[2 * r] = (bf16)s[2 * a][r];
        pb[2 * r + 1] = (bf16)s[2 * a + 1][r];
      }
      *(bf16x8*)(sP + prow * 256 + 16 * (((a << 2) + u) ^ pswz)) = pb;
    }
    __syncthreads();  // (1) P visible

    // ---- PV: 4 kb-groups x [4 P-frag reads + 16 mfma] ----
    __builtin_amdgcn_s_setprio(1);
#pragma unroll
    for (int kb = 0; kb < 4; ++kb) {
      bf16x8 pbr[4];
#pragma unroll
      for (int pg = 0; pg < 4; ++pg) {
        const int rr = (pg << 4) + l16;
        pbr[pg] = *(const bf16x8*)(sP + rr * 256 + 16 * (((kb << 2) + u) ^ (rr & 7)));
      }
#pragma unroll
      for (int ct = 0; ct < 4; ++ct)
#pragma unroll
        for (int pg = 0; pg < 4; ++pg)
          acc[pg][ct] = MFMA16(vr[(kb << 2) + ct], pbr[pg], acc[pg][ct]);
    }
    __builtin_amdgcn_s_setprio(0);
    asm volatile("s_waitcnt vmcnt(0)" ::: "memory");
    __syncthreads();  // (2) K_{t+1} landed; sP/sK reads done
    cur ^= 1;
  }

  // ---- epilogue: share l, per-lane normalize, direct stores ----
  if (lane < 16) sL[(w << 4) + lane] = l_;
  __syncthreads();
#pragma unroll
  for (int pg = 0; pg < 4; ++pg) {
    const float inv = 1.f / sL[(pg << 4) + l16];
    float* ob = out + ((size_t)b << 18) + p0 + (pg << 4) + l16;
#pragma unroll
    for (int ct = 0; ct < 4; ++ct)
#pragma unroll
      for (int r = 0; r < 4; ++r) {
        int c = (w << 6) + (ct << 4) + (u << 2) + r;
        ob[(size_t)c << 10] = acc[pg][ct][r] * inv;
      }
  }
}

// ---------------------------------------------------------------------------
extern "C" void kernel_launch(void* const* d_in, const int* in_sizes, int n_in,
                              void* d_out, int out_size, void* d_ws, size_t ws_size,
                              hipStream_t stream) {
  const float* qf = (const float*)d_in[0];
  const float* kf = (const float*)d_in[1];
  const float* Wq = (const float*)d_in[2];
  const float* bq = (const float*)d_in[3];
  const float* Wk = (const float*)d_in[4];
  const float* bk = (const float*)d_in[5];
  // d_in[6] = vis_CA (unused)
  const int* flag = (const int*)d_in[7];  // same_WqWk
  float* out = (float*)d_out;

  char* ws = (char*)d_ws;
  bf16* Qp = (bf16*)ws;                          // 4 MiB: [32][1024][64] bf16
  bf16* Wbh = (bf16*)(ws + (4u << 20));          // 64 KiB
  bf16* Wbl = (bf16*)(ws + (4u << 20) + 65536);  // 64 KiB
  bf16* KV = (bf16*)(ws + (5u << 20));           // 20 MiB: [32][8] x 81920B chunks

  vprep_kernel<<<4128, 256, 0, stream>>>(kf, Wq, Wk, flag, KV, Wbh, Wbl);
  proj_kernel<<<dim3(8, 32, 2), 256, 0, stream>>>(qf, Wbh, Wbl, bq, bk, flag, Qp, KV);
  attn_kernel<<<512, 256, 0, stream>>>(KV, Qp, out);
}

// Round 21
// 65.492 us; speedup vs baseline: 1.8494x; 1.0913x over previous
//
#include <hip/hip_runtime.h>

typedef __bf16 bf16;
typedef __attribute__((ext_vector_type(4))) __bf16 bf16x4;
typedef __attribute__((ext_vector_type(8))) __bf16 bf16x8;
typedef __attribute__((ext_vector_type(4))) float f32x4;
typedef unsigned int u32;

#define MFMA16(a, b, c) __builtin_amdgcn_mfma_f32_16x16x32_bf16((a), (b), (c), 0, 0, 0)
#define LOG2E 1.4426950408889634f
#define AS1 __attribute__((address_space(1)))
#define AS3 __attribute__((address_space(3)))
#define GLL16(g, l) __builtin_amdgcn_global_load_lds((const AS1 u32*)(g), (AS3 u32*)(l), 16, 0, 0)

// KV chunk, per (b, kt=0..7): 81920 bytes =
//  [0,16384):     K tile [128 q][64 o] bf16, identity rows, 16B-blk swz ^(q&7)
//  [16384,81920): V packed for DIRECT wave-fragment loads: octet (c, mm)
//     (mm = kv>>3 within chunk) at byte 16384 + (c>>6)<<14 + (mm>>2)<<12 +
//     ((c>>4)&3)<<10 + (mm&3)<<8 + (c&15)<<4.  attn wave w: load k=4kb+ct at
//     (w<<14)+(k<<10)+(lane<<4) == A-frag (c=64w+16ct+l16, octet mm=4kb+u).

// ---------------------------------------------------------------------------
// Kernel 1: W hi/lo split only (tiny, 32 blocks).
// ---------------------------------------------------------------------------
__global__ __launch_bounds__(256) void wprep_kernel(const float* __restrict__ Wq,
                                                    const float* __restrict__ Wk,
                                                    const int* __restrict__ flag,
                                                    bf16* __restrict__ Wbh,
                                                    bf16* __restrict__ Wbl) {
  const int bx = blockIdx.x, t = threadIdx.x;
  int z = bx >> 4;
  const float* src = (z == 0) ? Wq : ((flag[0] != 0) ? Wq : Wk);
  const float sc = (z == 0) ? LOG2E : 1.0f;  // exp2-domain softmax
  int i = ((((bx & 15) << 8) + t) << 2);
  float4 vv = *(const float4*)(src + i);
  vv.x *= sc; vv.y *= sc; vv.z *= sc; vv.w *= sc;
  bf16x4 hi, lo;
  hi[0] = (bf16)vv.x; lo[0] = (bf16)(vv.x - (float)hi[0]);
  hi[1] = (bf16)vv.y; lo[1] = (bf16)(vv.y - (float)hi[1]);
  hi[2] = (bf16)vv.z; lo[2] = (bf16)(vv.z - (float)hi[2]);
  hi[3] = (bf16)vv.w; lo[3] = (bf16)(vv.w - (float)hi[3]);
  *(bf16x4*)(Wbh + (z << 14) + i) = hi;
  *(bf16x4*)(Wbl + (z << 14) + i) = lo;
}

// ---------------------------------------------------------------------------
// Kernel 2: MERGED proj + V-pack (independent work, one dispatch so the
// BW-bound V-pack overlaps the MFMA/latency-bound projection).
// blocks [0,512): projection. bx=bid: x=bx&7, b=(bx>>3)&31, z=bx>>8.
//   z=0 -> Qp (log2e-scaled); z=1 -> KV K-part (identity rows + blk swz).
//   B-frags: fp32 loads from qf/kf + inline cvt (bit-identical to V-pack's).
// blocks [512,4608): kf fp32 -> KV V-region bf16 packed (R12 verbatim).
// ---------------------------------------------------------------------------
__global__ __launch_bounds__(256) void prep_kernel(const float* __restrict__ qf,
                                                   const float* __restrict__ kf,
                                                   const bf16* __restrict__ Wbh,
                                                   const bf16* __restrict__ Wbl,
                                                   const float* __restrict__ bq,
                                                   const float* __restrict__ bk,
                                                   const int* __restrict__ flag,
                                                   bf16* __restrict__ Qp,
                                                   bf16* __restrict__ KV) {
  const int bid = blockIdx.x, t = threadIdx.x;
  if (bid >= 512) {
    // ---- V-pack: (b, c, q8) -> KV V-region, bf16, fragment-packed ----
    int i = ((bid - 512) << 8) + t;
    int q8 = i & 127, c = (i >> 7) & 255, b = i >> 15;
    const float* src = kf + ((size_t)(((b << 8) + c)) << 10) + (q8 << 3);
    float4 f0 = *(const float4*)src;
    float4 f1 = *(const float4*)(src + 4);
    bf16x8 v;
    v[0] = (bf16)f0.x; v[1] = (bf16)f0.y; v[2] = (bf16)f0.z; v[3] = (bf16)f0.w;
    v[4] = (bf16)f1.x; v[5] = (bf16)f1.y; v[6] = (bf16)f1.z; v[7] = (bf16)f1.w;
    int kt = q8 >> 4, mm = q8 & 15;
    char* dst = (char*)KV + (size_t)((b << 3) + kt) * 81920 + 16384 +
                ((c >> 6) << 14) + ((mm >> 2) << 12) + (((c >> 4) & 3) << 10) +
                ((mm & 3) << 8) + ((c & 15) << 4);
    *(bf16x8*)dst = v;
    return;
  }
  // ---- projection ----
  const int bx = bid;
  const int x = bx & 7, b = (bx >> 3) & 31, z = bx >> 8;
  const float* xg = z ? kf : qf;
  const bf16* Wh = Wbh + z * 16384;
  const bf16* Wl = Wbl + z * 16384;
  const float* bias = z ? (flag[0] ? bq : bk) : bq;

  const int w = t >> 6, lane = t & 63;
  const int g = lane >> 4, l16 = lane & 15;
  const int wo = w >> 1, wp = w & 1;
  const int o0 = wo << 5;
  const int pbase = (x << 7) + (wp << 6);

  f32x4 acc[2][4];
#pragma unroll
  for (int ot = 0; ot < 2; ++ot) {
    float4 bv = *(const float4*)(bias + o0 + (ot << 4) + (g << 2));
    if (z == 0) { bv.x *= LOG2E; bv.y *= LOG2E; bv.z *= LOG2E; bv.w *= LOG2E; }
#pragma unroll
    for (int pt = 0; pt < 4; ++pt) acc[ot][pt] = (f32x4){bv.x, bv.y, bv.z, bv.w};
  }

  const float* xb = xg + ((((b << 8) + (g << 3)) << 10) + pbase + l16);
  const bf16* whb = Wh + ((o0 + l16) << 8) + (g << 3);
  const bf16* wlb = Wl + ((o0 + l16) << 8) + (g << 3);

  for (int kk = 0; kk < 8; ++kk) {
    bf16x8 ah[2], al[2];
#pragma unroll
    for (int ot = 0; ot < 2; ++ot) {
      ah[ot] = *(const bf16x8*)(whb + (ot << 12) + (kk << 5));
      al[ot] = *(const bf16x8*)(wlb + (ot << 12) + (kk << 5));
    }
    const float* xk = xb + (kk << 15);
#pragma unroll
    for (int pt = 0; pt < 4; ++pt) {
      float xv[8];
#pragma unroll
      for (int j = 0; j < 8; ++j) xv[j] = xk[(j << 10) + (pt << 4)];
      bf16x8 xf;
#pragma unroll
      for (int j = 0; j < 8; ++j) xf[j] = (bf16)xv[j];
#pragma unroll
      for (int ot = 0; ot < 2; ++ot) {
        acc[ot][pt] = MFMA16(ah[ot], xf, acc[ot][pt]);
        acc[ot][pt] = MFMA16(al[ot], xf, acc[ot][pt]);
      }
    }
  }

#pragma unroll
  for (int ot = 0; ot < 2; ++ot)
#pragma unroll
    for (int pt = 0; pt < 4; ++pt) {
      bf16x4 q4;
#pragma unroll
      for (int r = 0; r < 4; ++r) q4[r] = (bf16)acc[ot][pt][r];
      int p = pbase + (pt << 4) + l16;
      if (z == 0) {
        *(bf16x4*)(Qp + ((((b << 10) + p)) << 6) + o0 + (ot << 4) + (g << 2)) = q4;
      } else {
        int kt = p >> 7, q = p & 127;
        int blk = (o0 >> 3) + (ot << 1) + (g >> 1);
        char* dst = (char*)KV + (size_t)((b << 3) + kt) * 81920 + q * 128 +
                    16 * (blk ^ (q & 7)) + ((g & 1) << 3);
        *(bf16x4*)dst = q4;
      }
    }
}

// ---------------------------------------------------------------------------
// Kernel 3: fused flash attention (R12 verbatim). grid 512 (XCD-swz) x 256.
// KVBLK=128, 8 iters, no-max exp2 softmax, V global->VGPR packed frags,
// P via sP (in-lane octets), K gll dbuf, 2 barriers/iter.
// ---------------------------------------------------------------------------
__global__ __launch_bounds__(256, 2) void attn_kernel(const bf16* __restrict__ KV,
                                                      const bf16* __restrict__ Qp,
                                                      float* __restrict__ out) {
  const int bid = blockIdx.x;
  const int wkid = ((bid & 7) << 6) + (bid >> 3);  // bijective: 512 % 8 == 0
  const int b = wkid >> 4, ptile = wkid & 15;
  const int p0 = ptile << 6;
  const int t = threadIdx.x;
  const int w = t >> 6, lane = t & 63;
  const int u = lane >> 4, l16 = lane & 15;

  __shared__ __align__(16) unsigned char sK[2][16384];  // K dbuf (gll target)
  __shared__ __align__(16) unsigned char sP[16384];     // [64 px][128 kv], swz
  __shared__ float sL[64];

  // Q B-fragments for this wave's 16 px (col=px, k=o)
  const bf16* qb = Qp + (((size_t)((b << 10) + p0 + (w << 4) + l16)) << 6) + (u << 3);
  const bf16x8 qa0 = *(const bf16x8*)qb;
  const bf16x8 qa1 = *(const bf16x8*)(qb + 32);

  const char* chunk0 = (const char*)KV + (size_t)b * (8 * 81920);
  const int Rb = ((l16 >> 2) << 3) + ((l16 & 3) << 1);  // K row perm base

  f32x4 acc[4][4];  // [pg][ct]: c = 64w + 16ct + 4u + r ; px = 16pg + l16
#pragma unroll
  for (int i = 0; i < 4; ++i)
#pragma unroll
    for (int j = 0; j < 4; ++j) acc[i][j] = (f32x4){0.f, 0.f, 0.f, 0.f};
  float l_ = 0.f;

  const int prow = (w << 4) + l16, pswz = prow & 7;

  // ---- prologue: stage K_0 (4 gll/wave) ----
  {
    const char* g = chunk0 + (w << 12) + (lane << 4);
    unsigned char* l = sK[0] + (w << 12);
#pragma unroll
    for (int op = 0; op < 4; ++op) GLL16(g + op * 1024, l + op * 1024);
  }
  asm volatile("s_waitcnt vmcnt(0)" ::: "memory");
  __syncthreads();

  int cur = 0;
  for (int kt = 0; kt < 8; ++kt) {
    // ---- V_t -> regs: 16 coalesced 1KB loads (packed A-fragments) ----
    bf16x8 vr[16];  // vr[4kb+ct] = V A-frag (c=64w+16ct+l16, octet 4kb+u)
    const char* vsrc = chunk0 + kt * 81920 + 16384 + (w << 14) + (lane << 4);
#pragma unroll
    for (int k = 0; k < 16; ++k) vr[k] = *(const bf16x8*)(vsrc + (k << 10));
    // ---- K_{t+1} gll into other buffer ----
    if (kt < 7) {
      const char* g = chunk0 + (kt + 1) * 81920 + (w << 12) + (lane << 4);
      unsigned char* l = sK[cur ^ 1] + (w << 12);
#pragma unroll
      for (int op = 0; op < 4; ++op) GLL16(g + op * 1024, l + op * 1024);
    }
    const unsigned char* sKc = sK[cur];

    // ---- S^T = K·Q^T (16 mfma, permuted K rows from swizzled LDS) ----
    f32x4 s[8];
#pragma unroll
    for (int qt = 0; qt < 8; ++qt) {
      const int R = Rb + (qt & 1) + ((qt >> 1) << 5);
      const int rb = R * 128;
      bf16x8 k0 = *(const bf16x8*)(sKc + rb + 16 * (u ^ (R & 7)));
      bf16x8 k1 = *(const bf16x8*)(sKc + rb + 16 * ((u + 4) ^ (R & 7)));
      f32x4 z = (f32x4){0.f, 0.f, 0.f, 0.f};
      z = MFMA16(k0, qa0, z);
      s[qt] = MFMA16(k1, qa1, z);
    }
    // ---- NO-MAX softmax: P = exp2(S); l += sum ----
#pragma unroll
    for (int qt = 0; qt < 8; ++qt)
#pragma unroll
      for (int r = 0; r < 4; ++r) s[qt][r] = exp2f(s[qt][r]);
    float rs = 0.f;
#pragma unroll
    for (int qt = 0; qt < 8; ++qt)
      rs += (s[qt][0] + s[qt][1]) + (s[qt][2] + s[qt][3]);
    rs += __shfl_xor(rs, 16);
    rs += __shfl_xor(rs, 32);
    l_ += rs;
    // ---- P -> bf16 octets (in-lane), publish 4 b128 ----
#pragma unroll
    for (int a = 0; a < 4; ++a) {
      bf16x8 pb;
#pragma unroll
      for (int r = 0; r < 4; ++r) {
        pb[2 * r] = (bf16)s[2 * a][r];
        pb[2 * r + 1] = (bf16)s[2 * a + 1][r];
      }
      *(bf16x8*)(sP + prow * 256 + 16 * (((a << 2) + u) ^ pswz)) = pb;
    }
    __syncthreads();  // (1) P visible

    // ---- PV: 4 kb-groups x [4 P-frag reads + 16 mfma] ----
#pragma unroll
    for (int kb = 0; kb < 4; ++kb) {
      bf16x8 pbr[4];
#pragma unroll
      for (int pg = 0; pg < 4; ++pg) {
        const int rr = (pg << 4) + l16;
        pbr[pg] = *(const bf16x8*)(sP + rr * 256 + 16 * (((kb << 2) + u) ^ (rr & 7)));
      }
#pragma unroll
      for (int ct = 0; ct < 4; ++ct)
#pragma unroll
        for (int pg = 0; pg < 4; ++pg)
          acc[pg][ct] = MFMA16(vr[(kb << 2) + ct], pbr[pg], acc[pg][ct]);
    }
    asm volatile("s_waitcnt vmcnt(0)" ::: "memory");
    __syncthreads();  // (2) K_{t+1} landed; sP/sK reads done
    cur ^= 1;
  }

  // ---- epilogue: share l, per-lane normalize, direct stores ----
  if (lane < 16) sL[(w << 4) + lane] = l_;
  __syncthreads();
#pragma unroll
  for (int pg = 0; pg < 4; ++pg) {
    const float inv = 1.f / sL[(pg << 4) + l16];
    float* ob = out + ((size_t)b << 18) + p0 + (pg << 4) + l16;
#pragma unroll
    for (int ct = 0; ct < 4; ++ct)
#pragma unroll
      for (int r = 0; r < 4; ++r) {
        int c = (w << 6) + (ct << 4) + (u << 2) + r;
        ob[(size_t)c << 10] = acc[pg][ct][r] * inv;
      }
  }
}

// ---------------------------------------------------------------------------
extern "C" void kernel_launch(void* const* d_in, const int* in_sizes, int n_in,
                              void* d_out, int out_size, void* d_ws, size_t ws_size,
                              hipStream_t stream) {
  const float* qf = (const float*)d_in[0];
  const float* kf = (const float*)d_in[1];
  const float* Wq = (const float*)d_in[2];
  const float* bq = (const float*)d_in[3];
  const float* Wk = (const float*)d_in[4];
  const float* bk = (const float*)d_in[5];
  // d_in[6] = vis_CA (unused)
  const int* flag = (const int*)d_in[7];  // same_WqWk
  float* out = (float*)d_out;

  char* ws = (char*)d_ws;
  bf16* Qp = (bf16*)ws;                          // 4 MiB: [32][1024][64] bf16
  bf16* Wbh = (bf16*)(ws + (4u << 20));          // 64 KiB
  bf16* Wbl = (bf16*)(ws + (4u << 20) + 65536);  // 64 KiB
  bf16* KV = (bf16*)(ws + (5u << 20));           // 20 MiB: [32][8] x 81920B chunks

  wprep_kernel<<<32, 256, 0, stream>>>(Wq, Wk, flag, Wbh, Wbl);
  prep_kernel<<<4608, 256, 0, stream>>>(qf, kf, Wbh, Wbl, bq, bk, flag, Qp, KV);
  attn_kernel<<<512, 256, 0, stream>>>(KV, Qp, out);
}